// Round 1
// baseline (2118.047 us; speedup 1.0000x reference)
//
#include <hip/hip_runtime.h>

#define NODE_DIM 128
#define HDIM 64
#define EDGE_DIM 32

// ---- degree count: deg[dst] += 1 per edge (exact: sums of 1.0f) ----
__global__ __launch_bounds__(256) void k_deg(const int* __restrict__ dst,
                                             float* __restrict__ deg, int E) {
    int e = blockIdx.x * 256 + threadIdx.x;
    if (e < E) atomicAdd(&deg[dst[e]], 1.0f);
}

// ---- dinv = 1/sqrt(deg + 1)   (self-loop adds 1; deg>=1 always) ----
__global__ __launch_bounds__(256) void k_dinv(float* deg, int n) {
    int i = blockIdx.x * 256 + threadIdx.x;
    if (i < n) deg[i] = 1.0f / sqrtf(deg[i] + 1.0f);
}

// ---- node embedding: h = x @ W_node + b_node   [N,128]x[128,64] ----
__global__ __launch_bounds__(256) void k_node_embed(const float* __restrict__ x,
        const float* __restrict__ W, const float* __restrict__ b,
        float* __restrict__ h, int n) {
    __shared__ float xs[4][NODE_DIM];
    int g = threadIdx.x >> 6, o = threadIdx.x & 63;
    int node = blockIdx.x * 4 + g;
    bool valid = node < n;
    if (valid) {
        const float* xr = x + (size_t)node * NODE_DIM;
        xs[g][o]      = xr[o];
        xs[g][o + 64] = xr[o + 64];
    }
    __syncthreads();
    if (!valid) return;
    float acc = b[o];
#pragma unroll
    for (int k = 0; k < NODE_DIM; k++) acc = fmaf(xs[g][k], W[k * HDIM + o], acc);
    h[(size_t)node * HDIM + o] = acc;
}

// ---- edge embedding scattered to source node: h[src] += ea@W_edge + b_edge ----
__global__ __launch_bounds__(256) void k_edge_embed(const float* __restrict__ ea,
        const int* __restrict__ src, const float* __restrict__ W,
        const float* __restrict__ b, float* __restrict__ h, int E) {
    __shared__ float es[4][EDGE_DIM];
    int g = threadIdx.x >> 6, o = threadIdx.x & 63;
    int e = blockIdx.x * 4 + g;
    bool valid = e < E;
    if (valid && o < EDGE_DIM) es[g][o] = ea[(size_t)e * EDGE_DIM + o];
    __syncthreads();
    if (!valid) return;
    float acc = b[o];
#pragma unroll
    for (int k = 0; k < EDGE_DIM; k++) acc = fmaf(es[g][k], W[k * HDIM + o], acc);
    atomicAdd(&h[(size_t)src[e] * HDIM + o], acc);
}

// ---- GCN matmul + finalize-previous-layer fusion.
// MODE 0: hin = in[node] directly (conv1: h0 already has bias+edge agg)
// MODE 1: hin = relu(dinv[node]*in[node] + bin)   (finalize of previous conv)
// Writes g = dinv[node] * (hin @ W) to gbuf, and initializes accbuf = g
// (the self-loop contribution, since out[n] = dinv[n]*(sum g[src] + g[n]) + b).
template <int MODE>
__global__ __launch_bounds__(256) void k_gcn_mm(const float* __restrict__ in,
        const float* __restrict__ bin, const float* __restrict__ dinv,
        const float* __restrict__ W, float* __restrict__ gbuf,
        float* __restrict__ accbuf, int n) {
    __shared__ float hs[4][HDIM];
    int g = threadIdx.x >> 6, o = threadIdx.x & 63;
    int node = blockIdx.x * 4 + g;
    bool valid = node < n;
    float di = 0.0f;
    if (valid) {
        di = dinv[node];
        float v = in[(size_t)node * HDIM + o];
        if (MODE == 1) v = fmaxf(fmaf(di, v, bin[o]), 0.0f);
        hs[g][o] = v;
    }
    __syncthreads();
    if (!valid) return;
    float acc = 0.0f;
#pragma unroll
    for (int k = 0; k < HDIM; k++) acc = fmaf(hs[g][k], W[k * HDIM + o], acc);
    acc *= di;
    size_t idx = (size_t)node * HDIM + o;
    gbuf[idx]   = acc;
    accbuf[idx] = acc;
}

// ---- propagate: acc[dst] += g[src] over all edges ----
__global__ __launch_bounds__(256) void k_gcn_scatter(const int* __restrict__ src,
        const int* __restrict__ dst, const float* __restrict__ gbuf,
        float* __restrict__ acc, int E) {
    int g = threadIdx.x >> 6, o = threadIdx.x & 63;
    int e = blockIdx.x * 4 + g;
    if (e >= E) return;
    float v = gbuf[(size_t)src[e] * HDIM + o];
    atomicAdd(&acc[(size_t)dst[e] * HDIM + o], v);
}

// ---- finalize conv3 + global mean-pool accumulation ----
__global__ __launch_bounds__(256) void k_pool(const float* __restrict__ acc3,
        const float* __restrict__ bin, const float* __restrict__ dinv,
        const int* __restrict__ batch, float* __restrict__ sums,
        float* __restrict__ cnts, int n) {
    int g = threadIdx.x >> 6, o = threadIdx.x & 63;
    int node = blockIdx.x * 4 + g;
    if (node >= n) return;
    float v = fmaf(dinv[node], acc3[(size_t)node * HDIM + o], bin[o]);
    int b = batch[node];
    atomicAdd(&sums[(size_t)b * HDIM + o], v);
    if (o == 0) atomicAdd(&cnts[b], 1.0f);
}

// ---- classifier: out = relu(mean @ Wc1 + bc1) @ Wc2 + bc2, one wave/graph ----
__global__ __launch_bounds__(64) void k_cls(const float* __restrict__ sums,
        const float* __restrict__ cnts, const float* __restrict__ W1,
        const float* __restrict__ b1, const float* __restrict__ W2,
        const float* __restrict__ b2, float* __restrict__ out) {
    __shared__ float gs[HDIM];
    __shared__ float zs[32];
    int b = blockIdx.x, t = threadIdx.x;
    float cnt = fmaxf(cnts[b], 1.0f);
    gs[t] = sums[(size_t)b * HDIM + t] / cnt;
    __syncthreads();
    if (t < 32) {
        float a = b1[t];
#pragma unroll
        for (int k = 0; k < HDIM; k++) a = fmaf(gs[k], W1[k * 32 + t], a);
        zs[t] = fmaxf(a, 0.0f);
    }
    __syncthreads();
    if (t == 0) {
        float a = b2[0];
#pragma unroll
        for (int k = 0; k < 32; k++) a = fmaf(zs[k], W2[k], a);
        out[b] = a;
    }
}

extern "C" void kernel_launch(void* const* d_in, const int* in_sizes, int n_in,
                              void* d_out, int out_size, void* d_ws, size_t ws_size,
                              hipStream_t stream) {
    const float* x      = (const float*)d_in[0];
    const int*   ei     = (const int*)d_in[1];   // [2,E]: src = ei[0..E), dst = ei[E..2E)
    const float* ea     = (const float*)d_in[2];
    const int*   batch  = (const int*)d_in[3];
    const float* W_node = (const float*)d_in[4];
    const float* b_node = (const float*)d_in[5];
    const float* W_edge = (const float*)d_in[6];
    const float* b_edge = (const float*)d_in[7];
    const float* W_g1   = (const float*)d_in[8];
    const float* b_g1   = (const float*)d_in[9];
    const float* W_g2   = (const float*)d_in[10];
    const float* b_g2   = (const float*)d_in[11];
    const float* W_g3   = (const float*)d_in[12];
    const float* b_g3   = (const float*)d_in[13];
    const float* W_c1   = (const float*)d_in[14];
    const float* b_c1   = (const float*)d_in[15];
    const float* W_c2   = (const float*)d_in[16];
    const float* b_c2   = (const float*)d_in[17];

    const int N = in_sizes[0] / NODE_DIM;
    const int E = in_sizes[2] / EDGE_DIM;
    const int G = out_size;

    // workspace carve-out (256B aligned): dinv, A, B, C, sums, cnts  (~77 MB)
    char* ws = (char*)d_ws;
    size_t off = 0;
    auto carve = [&](size_t bytes) -> void* {
        void* p = ws + off;
        off += (bytes + 255) & ~(size_t)255;
        return p;
    };
    float* dinv = (float*)carve((size_t)N * 4);
    float* A    = (float*)carve((size_t)N * HDIM * 4);
    float* B    = (float*)carve((size_t)N * HDIM * 4);
    float* C    = (float*)carve((size_t)N * HDIM * 4);
    float* sums = (float*)carve((size_t)G * HDIM * 4);
    float* cnts = (float*)carve((size_t)G * 4);

    hipMemsetAsync(dinv, 0, (size_t)N * 4, stream);
    hipMemsetAsync(sums, 0, (size_t)G * HDIM * 4, stream);
    hipMemsetAsync(cnts, 0, (size_t)G * 4, stream);

    const int nb_nodes = (N + 3) / 4;
    const int nb_edges = (E + 3) / 4;

    // degrees -> dinv
    k_deg<<<(E + 255) / 256, 256, 0, stream>>>(ei + E, dinv, E);
    k_dinv<<<(N + 255) / 256, 256, 0, stream>>>(dinv, N);

    // node embed into A, then edge embed scattered into A
    k_node_embed<<<nb_nodes, 256, 0, stream>>>(x, W_node, b_node, A, N);
    k_edge_embed<<<nb_edges, 256, 0, stream>>>(ea, ei, W_edge, b_edge, A, E);

    // conv1: A -> (B,C);  C += B[src]
    k_gcn_mm<0><<<nb_nodes, 256, 0, stream>>>(A, nullptr, dinv, W_g1, B, C, N);
    k_gcn_scatter<<<nb_edges, 256, 0, stream>>>(ei, ei + E, B, C, E);

    // conv2: relu(dinv*C + b_g1) -> (B,A);  A += B[src]
    k_gcn_mm<1><<<nb_nodes, 256, 0, stream>>>(C, b_g1, dinv, W_g2, B, A, N);
    k_gcn_scatter<<<nb_edges, 256, 0, stream>>>(ei, ei + E, B, A, E);

    // conv3: relu(dinv*A + b_g2) -> (B,C);  C += B[src]
    k_gcn_mm<1><<<nb_nodes, 256, 0, stream>>>(A, b_g2, dinv, W_g3, B, C, N);
    k_gcn_scatter<<<nb_edges, 256, 0, stream>>>(ei, ei + E, B, C, E);

    // finalize conv3 (dinv*C + b_g3) + mean pool, then classifier
    k_pool<<<nb_nodes, 256, 0, stream>>>(C, b_g3, dinv, batch, sums, cnts, N);
    k_cls<<<G, 64, 0, stream>>>(sums, cnts, W_c1, b_c1, W_c2, b_c2, (float*)d_out);
}

// Round 2
// 1308.222 us; speedup vs baseline: 1.6190x; 1.6190x over previous
//
#include <hip/hip_runtime.h>

#define NODE_DIM 128
#define HDIM 64
#define EDGE_DIM 32
#define SCAN_BS 512
// NOTE: scan supports n <= SCAN_BS*256 = 131072; N = 100000 fits.

// ---- degree count (int atomics): in-degree at dst, out-degree at src ----
__global__ __launch_bounds__(256) void k_deg(const int* __restrict__ src,
        const int* __restrict__ dst, int* __restrict__ deg_in,
        int* __restrict__ cnt_out, int E) {
    int e = blockIdx.x * 256 + threadIdx.x;
    if (e < E) {
        atomicAdd(&deg_in[dst[e]], 1);
        atomicAdd(&cnt_out[src[e]], 1);
    }
}

// ---- dinv = 1/sqrt(in_deg + 1)  (self-loop; deg >= 1 always) ----
__global__ __launch_bounds__(256) void k_dinv(const int* __restrict__ deg_in,
        float* __restrict__ dinv, int n) {
    int i = blockIdx.x * 256 + threadIdx.x;
    if (i < n) dinv[i] = 1.0f / sqrtf((float)deg_in[i] + 1.0f);
}

// ---- 2-level exclusive scan (local pass) ----
__global__ __launch_bounds__(SCAN_BS) void k_scan_local(const int* __restrict__ in,
        int* __restrict__ out, int* __restrict__ bsum, int n) {
    __shared__ int tmp[SCAN_BS];
    int tid = threadIdx.x;
    int i = blockIdx.x * SCAN_BS + tid;
    int v = (i < n) ? in[i] : 0;
    tmp[tid] = v;
    __syncthreads();
    for (int off = 1; off < SCAN_BS; off <<= 1) {
        int t = (tid >= off) ? tmp[tid - off] : 0;
        __syncthreads();
        tmp[tid] += t;
        __syncthreads();
    }
    if (i < n) out[i] = tmp[tid] - v;                 // exclusive
    if (tid == SCAN_BS - 1) bsum[blockIdx.x] = tmp[tid];
}

// ---- scan of block sums (single block, nb <= 256) ----
__global__ __launch_bounds__(256) void k_scan_top(int* __restrict__ bsum, int nb) {
    __shared__ int tmp[256];
    int tid = threadIdx.x;
    int v = (tid < nb) ? bsum[tid] : 0;
    tmp[tid] = v;
    __syncthreads();
    for (int off = 1; off < 256; off <<= 1) {
        int t = (tid >= off) ? tmp[tid - off] : 0;
        __syncthreads();
        tmp[tid] += t;
        __syncthreads();
    }
    if (tid < nb) bsum[tid] = tmp[tid] - v;           // exclusive block offsets
}

// ---- add block offsets; also write row[n] = total ----
__global__ __launch_bounds__(SCAN_BS) void k_scan_add(int* __restrict__ out,
        const int* __restrict__ bsum, int n, int total) {
    int i = blockIdx.x * SCAN_BS + threadIdx.x;
    if (i < n) out[i] += bsum[blockIdx.x];
    if (i == 0) out[n] = total;
}

// ---- CSR fill: csr_in_src grouped by dst; csr_out_e grouped by src ----
__global__ __launch_bounds__(256) void k_fill(const int* __restrict__ src,
        const int* __restrict__ dst, int* __restrict__ cur_in,
        int* __restrict__ cur_out, int* __restrict__ csr_in_src,
        int* __restrict__ csr_out_e, int E) {
    int e = blockIdx.x * 256 + threadIdx.x;
    if (e < E) {
        int s = src[e], d = dst[e];
        csr_in_src[atomicAdd(&cur_in[d], 1)] = s;
        csr_out_e[atomicAdd(&cur_out[s], 1)] = e;
    }
}

// ---- fused node embed: h = x@Wn + bn + (sum_out ea)@We + outdeg*be ----
__global__ __launch_bounds__(256) void k_embed(const float* __restrict__ x,
        const float* __restrict__ ea, const int* __restrict__ csr_out_e,
        const int* __restrict__ row_out,
        const float* __restrict__ Wn, const float* __restrict__ bn,
        const float* __restrict__ We, const float* __restrict__ be,
        float* __restrict__ h, int n) {
    __shared__ float xs[4][NODE_DIM];
    __shared__ float ss[4][EDGE_DIM];
    int g = threadIdx.x >> 6, o = threadIdx.x & 63;
    int node = blockIdx.x * 4 + g;
    bool valid = node < n;
    float cout = 0.0f;
    if (valid) {
        const float* xr = x + (size_t)node * NODE_DIM;
        xs[g][o]      = xr[o];
        xs[g][o + 64] = xr[o + 64];
        int jb = row_out[node], je = row_out[node + 1];
        cout = (float)(je - jb);
        if (o < EDGE_DIM) {
            float s = 0.0f;
            for (int j = jb; j < je; j++) {
                int e = csr_out_e[j];
                s += ea[(size_t)e * EDGE_DIM + o];
            }
            ss[g][o] = s;
        }
    }
    __syncthreads();
    if (!valid) return;
    float acc = fmaf(cout, be[o], bn[o]);
#pragma unroll
    for (int k = 0; k < NODE_DIM; k++) acc = fmaf(xs[g][k], Wn[k * HDIM + o], acc);
#pragma unroll
    for (int k = 0; k < EDGE_DIM; k++) acc = fmaf(ss[g][k], We[k * HDIM + o], acc);
    h[(size_t)node * HDIM + o] = acc;
}

// ---- GCN matmul: g = dinv * (hin @ W), hin = MODE? relu(dinv*in + bin) : in ----
template <int MODE>
__global__ __launch_bounds__(256) void k_gcn_mm(const float* __restrict__ in,
        const float* __restrict__ bin, const float* __restrict__ dinv,
        const float* __restrict__ W, float* __restrict__ gbuf, int n) {
    __shared__ float hs[4][HDIM];
    int g = threadIdx.x >> 6, o = threadIdx.x & 63;
    int node = blockIdx.x * 4 + g;
    bool valid = node < n;
    float di = 0.0f;
    if (valid) {
        di = dinv[node];
        float v = in[(size_t)node * HDIM + o];
        if (MODE == 1) v = fmaxf(fmaf(di, v, bin[o]), 0.0f);
        hs[g][o] = v;
    }
    __syncthreads();
    if (!valid) return;
    float acc = 0.0f;
#pragma unroll
    for (int k = 0; k < HDIM; k++) acc = fmaf(hs[g][k], W[k * HDIM + o], acc);
    gbuf[(size_t)node * HDIM + o] = acc * di;
}

// ---- propagate by gather: out[n] = g[n] + sum_{in-edges} g[src] ----
__global__ __launch_bounds__(256) void k_gather(const int* __restrict__ csr_src,
        const int* __restrict__ row_in, const float* __restrict__ gbuf,
        float* __restrict__ out, int n) {
    int g = threadIdx.x >> 6, o = threadIdx.x & 63;
    int node = blockIdx.x * 4 + g;
    if (node >= n) return;
    int jb = row_in[node], je = row_in[node + 1];
    float acc = gbuf[(size_t)node * HDIM + o];      // self-loop
    int j = jb;
    for (; j + 4 <= je; j += 4) {
        int s0 = csr_src[j], s1 = csr_src[j + 1];
        int s2 = csr_src[j + 2], s3 = csr_src[j + 3];
        float v0 = gbuf[(size_t)s0 * HDIM + o];
        float v1 = gbuf[(size_t)s1 * HDIM + o];
        float v2 = gbuf[(size_t)s2 * HDIM + o];
        float v3 = gbuf[(size_t)s3 * HDIM + o];
        acc += v0 + v1 + v2 + v3;
    }
    for (; j < je; j++) acc += gbuf[(size_t)csr_src[j] * HDIM + o];
    out[(size_t)node * HDIM + o] = acc;
}

// ---- conv3 gather + finalize + global mean-pool accumulation ----
__global__ __launch_bounds__(256) void k_gather_pool(const int* __restrict__ csr_src,
        const int* __restrict__ row_in, const float* __restrict__ gbuf,
        const float* __restrict__ bin, const float* __restrict__ dinv,
        const int* __restrict__ batch, float* __restrict__ sums,
        float* __restrict__ cnts, int n) {
    int g = threadIdx.x >> 6, o = threadIdx.x & 63;
    int node = blockIdx.x * 4 + g;
    if (node >= n) return;
    int jb = row_in[node], je = row_in[node + 1];
    float acc = gbuf[(size_t)node * HDIM + o];
    int j = jb;
    for (; j + 4 <= je; j += 4) {
        int s0 = csr_src[j], s1 = csr_src[j + 1];
        int s2 = csr_src[j + 2], s3 = csr_src[j + 3];
        acc += gbuf[(size_t)s0 * HDIM + o] + gbuf[(size_t)s1 * HDIM + o]
             + gbuf[(size_t)s2 * HDIM + o] + gbuf[(size_t)s3 * HDIM + o];
    }
    for (; j < je; j++) acc += gbuf[(size_t)csr_src[j] * HDIM + o];
    float v = fmaf(dinv[node], acc, bin[o]);
    int b = batch[node];
    atomicAdd(&sums[(size_t)b * HDIM + o], v);
    if (o == 0) atomicAdd(&cnts[b], 1.0f);
}

// ---- classifier: out = relu(mean @ Wc1 + bc1) @ Wc2 + bc2 ----
__global__ __launch_bounds__(64) void k_cls(const float* __restrict__ sums,
        const float* __restrict__ cnts, const float* __restrict__ W1,
        const float* __restrict__ b1, const float* __restrict__ W2,
        const float* __restrict__ b2, float* __restrict__ out) {
    __shared__ float gs[HDIM];
    __shared__ float zs[32];
    int b = blockIdx.x, t = threadIdx.x;
    float cnt = fmaxf(cnts[b], 1.0f);
    gs[t] = sums[(size_t)b * HDIM + t] / cnt;
    __syncthreads();
    if (t < 32) {
        float a = b1[t];
#pragma unroll
        for (int k = 0; k < HDIM; k++) a = fmaf(gs[k], W1[k * 32 + t], a);
        zs[t] = fmaxf(a, 0.0f);
    }
    __syncthreads();
    if (t == 0) {
        float a = b2[0];
#pragma unroll
        for (int k = 0; k < 32; k++) a = fmaf(zs[k], W2[k], a);
        out[b] = a;
    }
}

extern "C" void kernel_launch(void* const* d_in, const int* in_sizes, int n_in,
                              void* d_out, int out_size, void* d_ws, size_t ws_size,
                              hipStream_t stream) {
    const float* x      = (const float*)d_in[0];
    const int*   ei     = (const int*)d_in[1];   // [2,E]: src = ei[0..E), dst = ei[E..2E)
    const float* ea     = (const float*)d_in[2];
    const int*   batch  = (const int*)d_in[3];
    const float* W_node = (const float*)d_in[4];
    const float* b_node = (const float*)d_in[5];
    const float* W_edge = (const float*)d_in[6];
    const float* b_edge = (const float*)d_in[7];
    const float* W_g1   = (const float*)d_in[8];
    const float* b_g1   = (const float*)d_in[9];
    const float* W_g2   = (const float*)d_in[10];
    const float* b_g2   = (const float*)d_in[11];
    const float* W_g3   = (const float*)d_in[12];
    const float* b_g3   = (const float*)d_in[13];
    const float* W_c1   = (const float*)d_in[14];
    const float* b_c1   = (const float*)d_in[15];
    const float* W_c2   = (const float*)d_in[16];
    const float* b_c2   = (const float*)d_in[17];

    const int N = in_sizes[0] / NODE_DIM;
    const int E = in_sizes[2] / EDGE_DIM;
    const int G = out_size;
    const int* src = ei;
    const int* dst = ei + E;

    // ---- workspace carve-out (256B aligned), ~93 MB total ----
    char* ws = (char*)d_ws;
    size_t off = 0;
    auto carve = [&](size_t bytes) -> void* {
        void* p = ws + off;
        off += (bytes + 255) & ~(size_t)255;
        return p;
    };
    int*   deg_in   = (int*)carve((size_t)N * 4);
    int*   cnt_out  = (int*)carve((size_t)N * 4);
    int*   row_in   = (int*)carve((size_t)(N + 1) * 4);
    int*   row_out  = (int*)carve((size_t)(N + 1) * 4);
    int*   cur_in   = (int*)carve((size_t)N * 4);
    int*   cur_out  = (int*)carve((size_t)N * 4);
    int*   bsum     = (int*)carve(1024);
    int*   csr_in_src = (int*)carve((size_t)E * 4);
    int*   csr_out_e  = (int*)carve((size_t)E * 4);
    float* dinv     = (float*)carve((size_t)N * 4);
    float* A        = (float*)carve((size_t)N * HDIM * 4);
    float* B        = (float*)carve((size_t)N * HDIM * 4);
    float* C        = (float*)carve((size_t)N * HDIM * 4);
    float* sums     = (float*)carve((size_t)G * HDIM * 4);
    float* cnts     = (float*)carve((size_t)G * 4);

    hipMemsetAsync(deg_in, 0, (size_t)N * 4, stream);
    hipMemsetAsync(cnt_out, 0, (size_t)N * 4, stream);
    hipMemsetAsync(sums, 0, (size_t)G * HDIM * 4, stream);
    hipMemsetAsync(cnts, 0, (size_t)G * 4, stream);

    const int nb_nodes = (N + 3) / 4;
    const int nb_e256  = (E + 255) / 256;
    const int nb_scan  = (N + SCAN_BS - 1) / SCAN_BS;   // 196 <= 256

    // degrees
    k_deg<<<nb_e256, 256, 0, stream>>>(src, dst, deg_in, cnt_out, E);
    k_dinv<<<(N + 255) / 256, 256, 0, stream>>>(deg_in, dinv, N);

    // exclusive scans -> row_in, row_out
    k_scan_local<<<nb_scan, SCAN_BS, 0, stream>>>(deg_in, row_in, bsum, N);
    k_scan_top<<<1, 256, 0, stream>>>(bsum, nb_scan);
    k_scan_add<<<nb_scan, SCAN_BS, 0, stream>>>(row_in, bsum, N, E);
    k_scan_local<<<nb_scan, SCAN_BS, 0, stream>>>(cnt_out, row_out, bsum, N);
    k_scan_top<<<1, 256, 0, stream>>>(bsum, nb_scan);
    k_scan_add<<<nb_scan, SCAN_BS, 0, stream>>>(row_out, bsum, N, E);

    // CSR fill (cursors = copies of row starts)
    hipMemcpyAsync(cur_in, row_in, (size_t)N * 4, hipMemcpyDeviceToDevice, stream);
    hipMemcpyAsync(cur_out, row_out, (size_t)N * 4, hipMemcpyDeviceToDevice, stream);
    k_fill<<<nb_e256, 256, 0, stream>>>(src, dst, cur_in, cur_out,
                                        csr_in_src, csr_out_e, E);

    // fused node+edge embedding -> A
    k_embed<<<nb_nodes, 256, 0, stream>>>(x, ea, csr_out_e, row_out,
                                          W_node, b_node, W_edge, b_edge, A, N);

    // conv1: A -> B (g), gather -> C
    k_gcn_mm<0><<<nb_nodes, 256, 0, stream>>>(A, nullptr, dinv, W_g1, B, N);
    k_gather<<<nb_nodes, 256, 0, stream>>>(csr_in_src, row_in, B, C, N);

    // conv2: relu(dinv*C + b_g1) -> B (g), gather -> A
    k_gcn_mm<1><<<nb_nodes, 256, 0, stream>>>(C, b_g1, dinv, W_g2, B, N);
    k_gather<<<nb_nodes, 256, 0, stream>>>(csr_in_src, row_in, B, A, N);

    // conv3: relu(dinv*A + b_g2) -> B (g), gather+finalize+pool
    k_gcn_mm<1><<<nb_nodes, 256, 0, stream>>>(A, b_g2, dinv, W_g3, B, N);
    k_gather_pool<<<nb_nodes, 256, 0, stream>>>(csr_in_src, row_in, B, b_g3,
                                                dinv, batch, sums, cnts, N);

    // classifier
    k_cls<<<G, 64, 0, stream>>>(sums, cnts, W_c1, b_c1, W_c2, b_c2, (float*)d_out);
}

// Round 3
// 954.831 us; speedup vs baseline: 2.2182x; 1.3701x over previous
//
#include <hip/hip_runtime.h>

#define NODE_DIM 128
#define HDIM 64
#define EDGE_DIM 32
#define SCAN_BS 512
// scan supports n <= SCAN_BS*256 = 131072; N = 100000 fits.

__device__ __forceinline__ void f4_add(float4& a, const float4 b) {
    a.x += b.x; a.y += b.y; a.z += b.z; a.w += b.w;
}
__device__ __forceinline__ void f4_shfl_xor_add(float4& a, int m) {
    a.x += __shfl_xor(a.x, m, 64);
    a.y += __shfl_xor(a.y, m, 64);
    a.z += __shfl_xor(a.z, m, 64);
    a.w += __shfl_xor(a.w, m, 64);
}

// ---- degree count (int atomics) ----
__global__ __launch_bounds__(256) void k_deg(const int* __restrict__ src,
        const int* __restrict__ dst, int* __restrict__ deg_in,
        int* __restrict__ cnt_out, int E) {
    int e = blockIdx.x * 256 + threadIdx.x;
    if (e < E) {
        atomicAdd(&deg_in[dst[e]], 1);
        atomicAdd(&cnt_out[src[e]], 1);
    }
}

__global__ __launch_bounds__(256) void k_dinv(const int* __restrict__ deg_in,
        float* __restrict__ dinv, int n) {
    int i = blockIdx.x * 256 + threadIdx.x;
    if (i < n) dinv[i] = 1.0f / sqrtf((float)deg_in[i] + 1.0f);
}

// ---- 2-level exclusive scan ----
__global__ __launch_bounds__(SCAN_BS) void k_scan_local(const int* __restrict__ in,
        int* __restrict__ out, int* __restrict__ bsum, int n) {
    __shared__ int tmp[SCAN_BS];
    int tid = threadIdx.x;
    int i = blockIdx.x * SCAN_BS + tid;
    int v = (i < n) ? in[i] : 0;
    tmp[tid] = v;
    __syncthreads();
    for (int off = 1; off < SCAN_BS; off <<= 1) {
        int t = (tid >= off) ? tmp[tid - off] : 0;
        __syncthreads();
        tmp[tid] += t;
        __syncthreads();
    }
    if (i < n) out[i] = tmp[tid] - v;
    if (tid == SCAN_BS - 1) bsum[blockIdx.x] = tmp[tid];
}

__global__ __launch_bounds__(256) void k_scan_top(int* __restrict__ bsum, int nb) {
    __shared__ int tmp[256];
    int tid = threadIdx.x;
    int v = (tid < nb) ? bsum[tid] : 0;
    tmp[tid] = v;
    __syncthreads();
    for (int off = 1; off < 256; off <<= 1) {
        int t = (tid >= off) ? tmp[tid - off] : 0;
        __syncthreads();
        tmp[tid] += t;
        __syncthreads();
    }
    if (tid < nb) bsum[tid] = tmp[tid] - v;
}

__global__ __launch_bounds__(SCAN_BS) void k_scan_add(int* __restrict__ out,
        const int* __restrict__ bsum, int n, int total) {
    int i = blockIdx.x * SCAN_BS + threadIdx.x;
    if (i < n) out[i] += bsum[blockIdx.x];
    if (i == 0) out[n] = total;
}

// ---- CSR fill ----
__global__ __launch_bounds__(256) void k_fill(const int* __restrict__ src,
        const int* __restrict__ dst, int* __restrict__ cur_in,
        int* __restrict__ cur_out, int* __restrict__ csr_in_src,
        int* __restrict__ csr_out_e, int E) {
    int e = blockIdx.x * 256 + threadIdx.x;
    if (e < E) {
        int s = src[e], d = dst[e];
        csr_in_src[atomicAdd(&cur_in[d], 1)] = s;
        csr_out_e[atomicAdd(&cur_out[s], 1)] = e;
    }
}

// ---- edge-attr segment sum by source: se[n][32] = sum_{out-edges} ea[e] ----
// wave per node; 8 edges x 8 float4-quads per iteration; indices preloaded+shfl
__global__ __launch_bounds__(256) void k_edge_sum(const float* __restrict__ ea,
        const int* __restrict__ csr_out_e, const int* __restrict__ row_out,
        float* __restrict__ se, int n) {
    int g = threadIdx.x >> 6, lane = threadIdx.x & 63;
    int slot = lane >> 3, dq = lane & 7;
    int node = blockIdx.x * 4 + g;
    if (node >= n) return;                    // wave-uniform, no syncthreads here
    int jb = row_out[node], je = row_out[node + 1];
    float4 acc = make_float4(0.f, 0.f, 0.f, 0.f);
    for (int base = jb; base < je; base += 64) {
        int cnt = min(64, je - base);
        int myidx = (base + lane < je) ? csr_out_e[base + lane] : 0;
#pragma unroll 2
        for (int t = 0; t < cnt; t += 8) {
            int which = t + slot;
            int e = __shfl(myidx, which, 64);
            if (which < cnt) {
                float4 v = *reinterpret_cast<const float4*>(
                    &ea[(size_t)e * EDGE_DIM + 4 * dq]);
                f4_add(acc, v);
            }
        }
    }
    f4_shfl_xor_add(acc, 8);
    f4_shfl_xor_add(acc, 16);
    f4_shfl_xor_add(acc, 32);
    if (slot == 0)
        *reinterpret_cast<float4*>(&se[(size_t)node * EDGE_DIM + 4 * dq]) = acc;
}

// ---- fused: h = x@Wn + bn + se@We + outdeg*be;  g1 = dinv*(h@W1) ----
__global__ __launch_bounds__(256) void k_embed_mm(const float* __restrict__ x,
        const float* __restrict__ se, const int* __restrict__ row_out,
        const float* __restrict__ Wn, const float* __restrict__ bn,
        const float* __restrict__ We, const float* __restrict__ be,
        const float* __restrict__ W1, const float* __restrict__ dinv,
        float* __restrict__ gout, int n) {
    __shared__ float xs[4][NODE_DIM];
    __shared__ float ss[4][EDGE_DIM];
    __shared__ float hs[4][HDIM];
    int g = threadIdx.x >> 6, o = threadIdx.x & 63;
    int node = blockIdx.x * 4 + g;
    bool valid = node < n;
    float cout = 0.f, di = 0.f;
    if (valid) {
        *reinterpret_cast<float2*>(&xs[g][2 * o]) =
            *reinterpret_cast<const float2*>(&x[(size_t)node * NODE_DIM + 2 * o]);
        if (o < EDGE_DIM) ss[g][o] = se[(size_t)node * EDGE_DIM + o];
        cout = (float)(row_out[node + 1] - row_out[node]);
        di = dinv[node];
    }
    __syncthreads();
    if (valid) {
        float h = fmaf(cout, be[o], bn[o]);
#pragma unroll
        for (int k = 0; k < NODE_DIM; k++) h = fmaf(xs[g][k], Wn[k * HDIM + o], h);
#pragma unroll
        for (int k = 0; k < EDGE_DIM; k++) h = fmaf(ss[g][k], We[k * HDIM + o], h);
        hs[g][o] = h;
    }
    __syncthreads();
    if (!valid) return;
    float a = 0.f;
#pragma unroll
    for (int k = 0; k < HDIM; k++) a = fmaf(hs[g][k], W1[k * HDIM + o], a);
    gout[(size_t)node * HDIM + o] = a * di;
}

// ---- fused gather + next-layer matmul:
// agg = g[node] + sum_{in-edges} g[src];  hin = relu(dinv*agg + bin);
// gout = dinv * (hin @ W)
__global__ __launch_bounds__(256) void k_gather_mm(const int* __restrict__ csr_src,
        const int* __restrict__ row_in, const float* __restrict__ gbuf,
        const float* __restrict__ bin, const float* __restrict__ dinv,
        const float* __restrict__ W, float* __restrict__ gout, int n) {
    __shared__ float hs[4][HDIM];
    int g = threadIdx.x >> 6, lane = threadIdx.x & 63;
    int slot = lane >> 4, dq = lane & 15;
    int node = blockIdx.x * 4 + g;
    bool valid = node < n;
    float di = 0.f;
    float4 acc = make_float4(0.f, 0.f, 0.f, 0.f);
    if (valid) {
        di = dinv[node];
        if (slot == 0)
            acc = *reinterpret_cast<const float4*>(&gbuf[(size_t)node * HDIM + 4 * dq]);
        int jb = row_in[node], je = row_in[node + 1];
        for (int base = jb; base < je; base += 64) {
            int cnt = min(64, je - base);
            int myidx = (base + lane < je) ? csr_src[base + lane] : 0;
#pragma unroll 2
            for (int t = 0; t < cnt; t += 4) {
                int which = t + slot;
                int e = __shfl(myidx, which, 64);
                if (which < cnt) {
                    float4 v = *reinterpret_cast<const float4*>(
                        &gbuf[(size_t)e * HDIM + 4 * dq]);
                    f4_add(acc, v);
                }
            }
        }
        f4_shfl_xor_add(acc, 16);
        f4_shfl_xor_add(acc, 32);
        if (slot == 0) {
            float4 bq = *reinterpret_cast<const float4*>(&bin[4 * dq]);
            float4 z;
            z.x = fmaxf(fmaf(di, acc.x, bq.x), 0.f);
            z.y = fmaxf(fmaf(di, acc.y, bq.y), 0.f);
            z.z = fmaxf(fmaf(di, acc.z, bq.z), 0.f);
            z.w = fmaxf(fmaf(di, acc.w, bq.w), 0.f);
            *reinterpret_cast<float4*>(&hs[g][4 * dq]) = z;
        }
    }
    __syncthreads();
    if (!valid) return;
    float a = 0.f;
#pragma unroll
    for (int k = 0; k < HDIM; k++) a = fmaf(hs[g][k], W[k * HDIM + lane], a);
    gout[(size_t)node * HDIM + lane] = a * di;
}

// ---- conv3 gather + finalize + mean-pool (block-merged atomics) ----
__global__ __launch_bounds__(256) void k_gather_pool(const int* __restrict__ csr_src,
        const int* __restrict__ row_in, const float* __restrict__ gbuf,
        const float* __restrict__ bin, const float* __restrict__ dinv,
        const int* __restrict__ batch, float* __restrict__ sums,
        float* __restrict__ cnts, int n) {
    __shared__ float vs[4][HDIM];
    __shared__ int bs[4];
    int g = threadIdx.x >> 6, lane = threadIdx.x & 63;
    int slot = lane >> 4, dq = lane & 15;
    int node = blockIdx.x * 4 + g;
    bool valid = node < n;
    float di = 0.f;
    int b = -1;
    float4 acc = make_float4(0.f, 0.f, 0.f, 0.f);
    if (valid) {
        di = dinv[node];
        b = batch[node];
        if (slot == 0)
            acc = *reinterpret_cast<const float4*>(&gbuf[(size_t)node * HDIM + 4 * dq]);
        int jb = row_in[node], je = row_in[node + 1];
        for (int base = jb; base < je; base += 64) {
            int cnt = min(64, je - base);
            int myidx = (base + lane < je) ? csr_src[base + lane] : 0;
#pragma unroll 2
            for (int t = 0; t < cnt; t += 4) {
                int which = t + slot;
                int e = __shfl(myidx, which, 64);
                if (which < cnt) {
                    float4 v = *reinterpret_cast<const float4*>(
                        &gbuf[(size_t)e * HDIM + 4 * dq]);
                    f4_add(acc, v);
                }
            }
        }
        f4_shfl_xor_add(acc, 16);
        f4_shfl_xor_add(acc, 32);
        if (slot == 0) {
            float4 bq = *reinterpret_cast<const float4*>(&bin[4 * dq]);
            float4 z;
            z.x = fmaf(di, acc.x, bq.x);
            z.y = fmaf(di, acc.y, bq.y);
            z.z = fmaf(di, acc.z, bq.z);
            z.w = fmaf(di, acc.w, bq.w);
            *reinterpret_cast<float4*>(&vs[g][4 * dq]) = z;
        }
    }
    if (lane == 0) bs[g] = b;
    __syncthreads();
    bool same = (bs[0] >= 0 && bs[0] == bs[1] && bs[1] == bs[2] && bs[2] == bs[3]);
    if (same) {
        if (g == 0) {
            float t = vs[0][lane] + vs[1][lane] + vs[2][lane] + vs[3][lane];
            atomicAdd(&sums[(size_t)bs[0] * HDIM + lane], t);
            if (lane == 0) atomicAdd(&cnts[bs[0]], 4.0f);
        }
    } else if (valid) {
        atomicAdd(&sums[(size_t)b * HDIM + lane], vs[g][lane]);
        if (lane == 0) atomicAdd(&cnts[b], 1.0f);
    }
}

// ---- classifier ----
__global__ __launch_bounds__(64) void k_cls(const float* __restrict__ sums,
        const float* __restrict__ cnts, const float* __restrict__ W1,
        const float* __restrict__ b1, const float* __restrict__ W2,
        const float* __restrict__ b2, float* __restrict__ out) {
    __shared__ float gs[HDIM];
    __shared__ float zs[32];
    int b = blockIdx.x, t = threadIdx.x;
    float cnt = fmaxf(cnts[b], 1.0f);
    gs[t] = sums[(size_t)b * HDIM + t] / cnt;
    __syncthreads();
    if (t < 32) {
        float a = b1[t];
#pragma unroll
        for (int k = 0; k < HDIM; k++) a = fmaf(gs[k], W1[k * 32 + t], a);
        zs[t] = fmaxf(a, 0.0f);
    }
    __syncthreads();
    if (t == 0) {
        float a = b2[0];
#pragma unroll
        for (int k = 0; k < 32; k++) a = fmaf(zs[k], W2[k], a);
        out[b] = a;
    }
}

extern "C" void kernel_launch(void* const* d_in, const int* in_sizes, int n_in,
                              void* d_out, int out_size, void* d_ws, size_t ws_size,
                              hipStream_t stream) {
    const float* x      = (const float*)d_in[0];
    const int*   ei     = (const int*)d_in[1];
    const float* ea     = (const float*)d_in[2];
    const int*   batch  = (const int*)d_in[3];
    const float* W_node = (const float*)d_in[4];
    const float* b_node = (const float*)d_in[5];
    const float* W_edge = (const float*)d_in[6];
    const float* b_edge = (const float*)d_in[7];
    const float* W_g1   = (const float*)d_in[8];
    const float* b_g1   = (const float*)d_in[9];
    const float* W_g2   = (const float*)d_in[10];
    const float* b_g2   = (const float*)d_in[11];
    const float* W_g3   = (const float*)d_in[12];
    const float* b_g3   = (const float*)d_in[13];
    const float* W_c1   = (const float*)d_in[14];
    const float* b_c1   = (const float*)d_in[15];
    const float* W_c2   = (const float*)d_in[16];
    const float* b_c2   = (const float*)d_in[17];

    const int N = in_sizes[0] / NODE_DIM;
    const int E = in_sizes[2] / EDGE_DIM;
    const int G = out_size;
    const int* src = ei;
    const int* dst = ei + E;

    char* ws = (char*)d_ws;
    size_t off = 0;
    auto carve = [&](size_t bytes) -> void* {
        void* p = ws + off;
        off += (bytes + 255) & ~(size_t)255;
        return p;
    };
    int*   deg_in     = (int*)carve((size_t)N * 4);
    int*   cnt_out    = (int*)carve((size_t)N * 4);
    int*   row_in     = (int*)carve((size_t)(N + 1) * 4);
    int*   row_out    = (int*)carve((size_t)(N + 1) * 4);
    int*   cur_in     = (int*)carve((size_t)N * 4);
    int*   cur_out    = (int*)carve((size_t)N * 4);
    int*   bsum       = (int*)carve(1024);
    int*   csr_in_src = (int*)carve((size_t)E * 4);
    int*   csr_out_e  = (int*)carve((size_t)E * 4);
    float* dinv       = (float*)carve((size_t)N * 4);
    float* se         = (float*)carve((size_t)N * EDGE_DIM * 4);
    float* B          = (float*)carve((size_t)N * HDIM * 4);
    float* C          = (float*)carve((size_t)N * HDIM * 4);
    float* sums       = (float*)carve((size_t)G * HDIM * 4);
    float* cnts       = (float*)carve((size_t)G * 4);

    hipMemsetAsync(deg_in, 0, (size_t)N * 4, stream);
    hipMemsetAsync(cnt_out, 0, (size_t)N * 4, stream);
    hipMemsetAsync(sums, 0, (size_t)G * HDIM * 4, stream);
    hipMemsetAsync(cnts, 0, (size_t)G * 4, stream);

    const int nb_nodes = (N + 3) / 4;
    const int nb_e256  = (E + 255) / 256;
    const int nb_scan  = (N + SCAN_BS - 1) / SCAN_BS;

    k_deg<<<nb_e256, 256, 0, stream>>>(src, dst, deg_in, cnt_out, E);
    k_dinv<<<(N + 255) / 256, 256, 0, stream>>>(deg_in, dinv, N);

    k_scan_local<<<nb_scan, SCAN_BS, 0, stream>>>(deg_in, row_in, bsum, N);
    k_scan_top<<<1, 256, 0, stream>>>(bsum, nb_scan);
    k_scan_add<<<nb_scan, SCAN_BS, 0, stream>>>(row_in, bsum, N, E);
    k_scan_local<<<nb_scan, SCAN_BS, 0, stream>>>(cnt_out, row_out, bsum, N);
    k_scan_top<<<1, 256, 0, stream>>>(bsum, nb_scan);
    k_scan_add<<<nb_scan, SCAN_BS, 0, stream>>>(row_out, bsum, N, E);

    hipMemcpyAsync(cur_in, row_in, (size_t)N * 4, hipMemcpyDeviceToDevice, stream);
    hipMemcpyAsync(cur_out, row_out, (size_t)N * 4, hipMemcpyDeviceToDevice, stream);
    k_fill<<<nb_e256, 256, 0, stream>>>(src, dst, cur_in, cur_out,
                                        csr_in_src, csr_out_e, E);

    // edge-attr segment sum, then fused embed + mm1 -> B (g1)
    k_edge_sum<<<nb_nodes, 256, 0, stream>>>(ea, csr_out_e, row_out, se, N);
    k_embed_mm<<<nb_nodes, 256, 0, stream>>>(x, se, row_out, W_node, b_node,
                                             W_edge, b_edge, W_g1, dinv, B, N);

    // conv1 gather + mm2 -> C (g2); conv2 gather + mm3 -> B (g3)
    k_gather_mm<<<nb_nodes, 256, 0, stream>>>(csr_in_src, row_in, B, b_g1, dinv,
                                              W_g2, C, N);
    k_gather_mm<<<nb_nodes, 256, 0, stream>>>(csr_in_src, row_in, C, b_g2, dinv,
                                              W_g3, B, N);

    // conv3 gather + finalize + pool, then classifier
    k_gather_pool<<<nb_nodes, 256, 0, stream>>>(csr_in_src, row_in, B, b_g3,
                                                dinv, batch, sums, cnts, N);
    k_cls<<<G, 64, 0, stream>>>(sums, cnts, W_c1, b_c1, W_c2, b_c2, (float*)d_out);
}

// Round 4
// 627.739 us; speedup vs baseline: 3.3741x; 1.5211x over previous
//
#include <hip/hip_runtime.h>

#define NODE_DIM 128
#define HDIM 64
#define EDGE_DIM 32
#define NB 256          // buckets for CSR binning
#define WMAX 512        // max nodes per bucket (N <= NB*WMAX = 131072)
#define EPB 4096        // edges per block in binning kernels

__device__ __forceinline__ void f4_add(float4& a, const float4 b) {
    a.x += b.x; a.y += b.y; a.z += b.z; a.w += b.w;
}
__device__ __forceinline__ void f4_shfl_xor_add(float4& a, int m) {
    a.x += __shfl_xor(a.x, m, 64);
    a.y += __shfl_xor(a.y, m, 64);
    a.z += __shfl_xor(a.z, m, 64);
    a.w += __shfl_xor(a.w, m, 64);
}

// ---- pass 1: per-bucket edge counts (dst-keyed and src-keyed) ----
__global__ __launch_bounds__(256) void k_bin_count(const int* __restrict__ src,
        const int* __restrict__ dst, int* __restrict__ countD,
        int* __restrict__ countS, int E, int W) {
    __shared__ int hD[NB], hS[NB];
    int t = threadIdx.x;
    hD[t] = 0; hS[t] = 0;
    __syncthreads();
    int lo = blockIdx.x * EPB, hi = min(lo + EPB, E);
    for (int e = lo + t; e < hi; e += 256) {
        atomicAdd(&hD[dst[e] / W], 1);
        atomicAdd(&hS[src[e] / W], 1);
    }
    __syncthreads();
    if (hD[t]) atomicAdd(&countD[t], hD[t]);
    if (hS[t]) atomicAdd(&countS[t], hS[t]);
}

// ---- bucket exclusive scan (1 block): bases + mutable cursors ----
__global__ __launch_bounds__(256) void k_bucket_scan(const int* __restrict__ countD,
        const int* __restrict__ countS, int* __restrict__ baseD,
        int* __restrict__ baseS, int* __restrict__ curD, int* __restrict__ curS,
        int E) {
    __shared__ int tmp[NB];
    int t = threadIdx.x;
    int v = countD[t]; tmp[t] = v; __syncthreads();
    for (int off = 1; off < NB; off <<= 1) {
        int u = (t >= off) ? tmp[t - off] : 0; __syncthreads();
        tmp[t] += u; __syncthreads();
    }
    baseD[t] = tmp[t] - v; curD[t] = tmp[t] - v;
    if (t == NB - 1) baseD[NB] = E;
    __syncthreads();
    v = countS[t]; tmp[t] = v; __syncthreads();
    for (int off = 1; off < NB; off <<= 1) {
        int u = (t >= off) ? tmp[t - off] : 0; __syncthreads();
        tmp[t] += u; __syncthreads();
    }
    baseS[t] = tmp[t] - v; curS[t] = tmp[t] - v;
    if (t == NB - 1) baseS[NB] = E;
}

// ---- pass 2: scatter (key,val) pairs into bucket-grouped arrays ----
// per-(block,bucket) chunk reservation -> writes land in contiguous runs
__global__ __launch_bounds__(256) void k_bin_scatter(const int* __restrict__ src,
        const int* __restrict__ dst, int* __restrict__ curD, int* __restrict__ curS,
        int2* __restrict__ pairD, int2* __restrict__ pairS, int E, int W) {
    __shared__ int hD[NB], hS[NB], bD[NB], bS[NB], oD[NB], oS[NB];
    int t = threadIdx.x;
    hD[t] = 0; hS[t] = 0; oD[t] = 0; oS[t] = 0;
    __syncthreads();
    int lo = blockIdx.x * EPB, hi = min(lo + EPB, E);
    for (int e = lo + t; e < hi; e += 256) {
        atomicAdd(&hD[dst[e] / W], 1);
        atomicAdd(&hS[src[e] / W], 1);
    }
    __syncthreads();
    if (hD[t]) bD[t] = atomicAdd(&curD[t], hD[t]);
    if (hS[t]) bS[t] = atomicAdd(&curS[t], hS[t]);
    __syncthreads();
    for (int e = lo + t; e < hi; e += 256) {
        int s = src[e], d = dst[e];
        int kb = d / W;
        int p = bD[kb] + atomicAdd(&oD[kb], 1);
        pairD[p] = make_int2(d, s);
        kb = s / W;
        p = bS[kb] + atomicAdd(&oS[kb], 1);
        pairS[p] = make_int2(s, e);
    }
}

// ---- pass 3: per-bucket CSR build. One block per bucket.
// pairs[.x]=node key, pairs[.y]=value. Writes csr segment [base[b],base[b+1]),
// row[] prefix for bucket's nodes, and (optionally) dinv from in-degree.
__global__ __launch_bounds__(256) void k_build(const int2* __restrict__ pairs,
        const int* __restrict__ base, int* __restrict__ csr, int* __restrict__ row,
        float* __restrict__ dinv, int N, int W) {
    __shared__ int cnt[WMAX], pref[WMAX], cur[WMAX];
    int b = blockIdx.x, t = threadIdx.x;
    int nbase = b * W;
    int wlen = min(W, N - nbase);
    int pb = base[b], pe = base[b + 1];
    for (int i = t; i < W; i += 256) cnt[i] = 0;
    __syncthreads();
    for (int j = pb + t; j < pe; j += 256)
        atomicAdd(&cnt[pairs[j].x - nbase], 1);
    __syncthreads();
    if (t < 64) {                       // wave0 exclusive scan of cnt[0..W)
        int run = 0;
        for (int c = 0; c < W; c += 64) {
            int i = c + t;
            int v = (i < W) ? cnt[i] : 0;
            int s = v;
            for (int off = 1; off < 64; off <<= 1) {
                int u = __shfl_up(s, off, 64);
                if (t >= off) s += u;
            }
            if (i < W) pref[i] = run + s - v;
            run += __shfl(s, 63, 64);
        }
    }
    __syncthreads();
    for (int i = t; i < wlen; i += 256) {
        row[nbase + i] = pb + pref[i];
        cur[i] = pref[i];
        if (dinv) dinv[nbase + i] = 1.0f / sqrtf((float)cnt[i] + 1.0f);
    }
    if (b == gridDim.x - 1 && t == 0) row[N] = pe;
    __syncthreads();
    for (int j = pb + t; j < pe; j += 256) {
        int2 pr = pairs[j];
        int idx = atomicAdd(&cur[pr.x - nbase], 1);
        csr[pb + idx] = pr.y;
    }
}

// ---- edge-attr segment sum by source: se[n][32] ----
__global__ __launch_bounds__(256) void k_edge_sum(const float* __restrict__ ea,
        const int* __restrict__ csr_out_e, const int* __restrict__ row_out,
        float* __restrict__ se, int n) {
    int g = threadIdx.x >> 6, lane = threadIdx.x & 63;
    int slot = lane >> 3, dq = lane & 7;
    int node = blockIdx.x * 4 + g;
    if (node >= n) return;
    int jb = row_out[node], je = row_out[node + 1];
    float4 acc = make_float4(0.f, 0.f, 0.f, 0.f);
    for (int base = jb; base < je; base += 64) {
        int cnt = min(64, je - base);
        int myidx = (base + lane < je) ? csr_out_e[base + lane] : 0;
#pragma unroll 4
        for (int t = 0; t < cnt; t += 8) {
            int which = t + slot;
            int e = __shfl(myidx, which, 64);
            if (which < cnt) {
                float4 v = *reinterpret_cast<const float4*>(
                    &ea[(size_t)e * EDGE_DIM + 4 * dq]);
                f4_add(acc, v);
            }
        }
    }
    f4_shfl_xor_add(acc, 8);
    f4_shfl_xor_add(acc, 16);
    f4_shfl_xor_add(acc, 32);
    if (slot == 0)
        *reinterpret_cast<float4*>(&se[(size_t)node * EDGE_DIM + 4 * dq]) = acc;
}

// ---- fused: h = x@Wn + bn + se@We + outdeg*be;  g1 = dinv*(h@W1) ----
__global__ __launch_bounds__(256) void k_embed_mm(const float* __restrict__ x,
        const float* __restrict__ se, const int* __restrict__ row_out,
        const float* __restrict__ Wn, const float* __restrict__ bn,
        const float* __restrict__ We, const float* __restrict__ be,
        const float* __restrict__ W1, const float* __restrict__ dinv,
        float* __restrict__ gout, int n) {
    __shared__ float xs[4][NODE_DIM];
    __shared__ float ss[4][EDGE_DIM];
    __shared__ float hs[4][HDIM];
    int g = threadIdx.x >> 6, o = threadIdx.x & 63;
    int node = blockIdx.x * 4 + g;
    bool valid = node < n;
    float cout = 0.f, di = 0.f;
    if (valid) {
        *reinterpret_cast<float2*>(&xs[g][2 * o]) =
            *reinterpret_cast<const float2*>(&x[(size_t)node * NODE_DIM + 2 * o]);
        if (o < EDGE_DIM) ss[g][o] = se[(size_t)node * EDGE_DIM + o];
        cout = (float)(row_out[node + 1] - row_out[node]);
        di = dinv[node];
    }
    __syncthreads();
    if (valid) {
        float h = fmaf(cout, be[o], bn[o]);
#pragma unroll
        for (int k = 0; k < NODE_DIM; k++) h = fmaf(xs[g][k], Wn[k * HDIM + o], h);
#pragma unroll
        for (int k = 0; k < EDGE_DIM; k++) h = fmaf(ss[g][k], We[k * HDIM + o], h);
        hs[g][o] = h;
    }
    __syncthreads();
    if (!valid) return;
    float a = 0.f;
#pragma unroll
    for (int k = 0; k < HDIM; k++) a = fmaf(hs[g][k], W1[k * HDIM + o], a);
    gout[(size_t)node * HDIM + o] = a * di;
}

// ---- fused gather + next-layer matmul ----
__global__ __launch_bounds__(256) void k_gather_mm(const int* __restrict__ csr_src,
        const int* __restrict__ row_in, const float* __restrict__ gbuf,
        const float* __restrict__ bin, const float* __restrict__ dinv,
        const float* __restrict__ W, float* __restrict__ gout, int n) {
    __shared__ float hs[4][HDIM];
    int g = threadIdx.x >> 6, lane = threadIdx.x & 63;
    int slot = lane >> 4, dq = lane & 15;
    int node = blockIdx.x * 4 + g;
    bool valid = node < n;
    float di = 0.f;
    float4 acc = make_float4(0.f, 0.f, 0.f, 0.f);
    if (valid) {
        di = dinv[node];
        if (slot == 0)
            acc = *reinterpret_cast<const float4*>(&gbuf[(size_t)node * HDIM + 4 * dq]);
        int jb = row_in[node], je = row_in[node + 1];
        for (int base = jb; base < je; base += 64) {
            int cnt = min(64, je - base);
            int myidx = (base + lane < je) ? csr_src[base + lane] : 0;
#pragma unroll 4
            for (int t = 0; t < cnt; t += 4) {
                int which = t + slot;
                int e = __shfl(myidx, which, 64);
                if (which < cnt) {
                    float4 v = *reinterpret_cast<const float4*>(
                        &gbuf[(size_t)e * HDIM + 4 * dq]);
                    f4_add(acc, v);
                }
            }
        }
        f4_shfl_xor_add(acc, 16);
        f4_shfl_xor_add(acc, 32);
        if (slot == 0) {
            float4 bq = *reinterpret_cast<const float4*>(&bin[4 * dq]);
            float4 z;
            z.x = fmaxf(fmaf(di, acc.x, bq.x), 0.f);
            z.y = fmaxf(fmaf(di, acc.y, bq.y), 0.f);
            z.z = fmaxf(fmaf(di, acc.z, bq.z), 0.f);
            z.w = fmaxf(fmaf(di, acc.w, bq.w), 0.f);
            *reinterpret_cast<float4*>(&hs[g][4 * dq]) = z;
        }
    }
    __syncthreads();
    if (!valid) return;
    float a = 0.f;
#pragma unroll
    for (int k = 0; k < HDIM; k++) a = fmaf(hs[g][k], W[k * HDIM + lane], a);
    gout[(size_t)node * HDIM + lane] = a * di;
}

// ---- conv3 gather + finalize + mean-pool (block-merged atomics) ----
__global__ __launch_bounds__(256) void k_gather_pool(const int* __restrict__ csr_src,
        const int* __restrict__ row_in, const float* __restrict__ gbuf,
        const float* __restrict__ bin, const float* __restrict__ dinv,
        const int* __restrict__ batch, float* __restrict__ sums,
        float* __restrict__ cnts, int n) {
    __shared__ float vs[4][HDIM];
    __shared__ int bs[4];
    int g = threadIdx.x >> 6, lane = threadIdx.x & 63;
    int slot = lane >> 4, dq = lane & 15;
    int node = blockIdx.x * 4 + g;
    bool valid = node < n;
    float di = 0.f;
    int b = -1;
    float4 acc = make_float4(0.f, 0.f, 0.f, 0.f);
    if (valid) {
        di = dinv[node];
        b = batch[node];
        if (slot == 0)
            acc = *reinterpret_cast<const float4*>(&gbuf[(size_t)node * HDIM + 4 * dq]);
        int jb = row_in[node], je = row_in[node + 1];
        for (int base = jb; base < je; base += 64) {
            int cnt = min(64, je - base);
            int myidx = (base + lane < je) ? csr_src[base + lane] : 0;
#pragma unroll 4
            for (int t = 0; t < cnt; t += 4) {
                int which = t + slot;
                int e = __shfl(myidx, which, 64);
                if (which < cnt) {
                    float4 v = *reinterpret_cast<const float4*>(
                        &gbuf[(size_t)e * HDIM + 4 * dq]);
                    f4_add(acc, v);
                }
            }
        }
        f4_shfl_xor_add(acc, 16);
        f4_shfl_xor_add(acc, 32);
        if (slot == 0) {
            float4 bq = *reinterpret_cast<const float4*>(&bin[4 * dq]);
            float4 z;
            z.x = fmaf(di, acc.x, bq.x);
            z.y = fmaf(di, acc.y, bq.y);
            z.z = fmaf(di, acc.z, bq.z);
            z.w = fmaf(di, acc.w, bq.w);
            *reinterpret_cast<float4*>(&vs[g][4 * dq]) = z;
        }
    }
    if (lane == 0) bs[g] = b;
    __syncthreads();
    bool same = (bs[0] >= 0 && bs[0] == bs[1] && bs[1] == bs[2] && bs[2] == bs[3]);
    if (same) {
        if (g == 0) {
            float t = vs[0][lane] + vs[1][lane] + vs[2][lane] + vs[3][lane];
            atomicAdd(&sums[(size_t)bs[0] * HDIM + lane], t);
            if (lane == 0) atomicAdd(&cnts[bs[0]], 4.0f);
        }
    } else if (valid) {
        atomicAdd(&sums[(size_t)b * HDIM + lane], vs[g][lane]);
        if (lane == 0) atomicAdd(&cnts[b], 1.0f);
    }
}

// ---- classifier ----
__global__ __launch_bounds__(64) void k_cls(const float* __restrict__ sums,
        const float* __restrict__ cnts, const float* __restrict__ W1,
        const float* __restrict__ b1, const float* __restrict__ W2,
        const float* __restrict__ b2, float* __restrict__ out) {
    __shared__ float gs[HDIM];
    __shared__ float zs[32];
    int b = blockIdx.x, t = threadIdx.x;
    float cnt = fmaxf(cnts[b], 1.0f);
    gs[t] = sums[(size_t)b * HDIM + t] / cnt;
    __syncthreads();
    if (t < 32) {
        float a = b1[t];
#pragma unroll
        for (int k = 0; k < HDIM; k++) a = fmaf(gs[k], W1[k * 32 + t], a);
        zs[t] = fmaxf(a, 0.0f);
    }
    __syncthreads();
    if (t == 0) {
        float a = b2[0];
#pragma unroll
        for (int k = 0; k < 32; k++) a = fmaf(zs[k], W2[k], a);
        out[b] = a;
    }
}

extern "C" void kernel_launch(void* const* d_in, const int* in_sizes, int n_in,
                              void* d_out, int out_size, void* d_ws, size_t ws_size,
                              hipStream_t stream) {
    const float* x      = (const float*)d_in[0];
    const int*   ei     = (const int*)d_in[1];
    const float* ea     = (const float*)d_in[2];
    const int*   batch  = (const int*)d_in[3];
    const float* W_node = (const float*)d_in[4];
    const float* b_node = (const float*)d_in[5];
    const float* W_edge = (const float*)d_in[6];
    const float* b_edge = (const float*)d_in[7];
    const float* W_g1   = (const float*)d_in[8];
    const float* b_g1   = (const float*)d_in[9];
    const float* W_g2   = (const float*)d_in[10];
    const float* b_g2   = (const float*)d_in[11];
    const float* W_g3   = (const float*)d_in[12];
    const float* b_g3   = (const float*)d_in[13];
    const float* W_c1   = (const float*)d_in[14];
    const float* b_c1   = (const float*)d_in[15];
    const float* W_c2   = (const float*)d_in[16];
    const float* b_c2   = (const float*)d_in[17];

    const int N = in_sizes[0] / NODE_DIM;
    const int E = in_sizes[2] / EDGE_DIM;
    const int G = out_size;
    const int W = (N + NB - 1) / NB;   // bucket width (<= WMAX for N <= 131072)
    const int* src = ei;
    const int* dst = ei + E;

    char* ws = (char*)d_ws;
    size_t off = 0;
    auto carve = [&](size_t bytes) -> void* {
        void* p = ws + off;
        off += (bytes + 255) & ~(size_t)255;
        return p;
    };
    int*   counts     = (int*)carve((size_t)2 * NB * 4);          // countD | countS
    int*   baseD      = (int*)carve((size_t)(NB + 1) * 4);
    int*   baseS      = (int*)carve((size_t)(NB + 1) * 4);
    int*   curD       = (int*)carve((size_t)NB * 4);
    int*   curS       = (int*)carve((size_t)NB * 4);
    int*   row_in     = (int*)carve((size_t)(N + 1) * 4);
    int*   row_out    = (int*)carve((size_t)(N + 1) * 4);
    int*   csr_in_src = (int*)carve((size_t)E * 4);
    int*   csr_out_e  = (int*)carve((size_t)E * 4);
    float* dinv       = (float*)carve((size_t)N * 4);
    float* se         = (float*)carve((size_t)N * EDGE_DIM * 4);
    float* B          = (float*)carve((size_t)N * HDIM * 4);
    float* C          = (float*)carve((size_t)N * HDIM * 4);
    float* sums       = (float*)carve((size_t)G * HDIM * 4);
    float* cnts       = (float*)carve((size_t)G * 4);
    int*   countD = counts, *countS = counts + NB;
    // pair arrays alias B and C (pairs consumed before B/C are first written)
    int2*  pairD = (int2*)B;
    int2*  pairS = (int2*)C;

    hipMemsetAsync(counts, 0, (size_t)2 * NB * 4, stream);
    hipMemsetAsync(sums, 0, (size_t)G * HDIM * 4, stream);
    hipMemsetAsync(cnts, 0, (size_t)G * 4, stream);

    const int nb_nodes = (N + 3) / 4;
    const int nb_bin   = (E + EPB - 1) / EPB;

    // CSR construction via bucket binning
    k_bin_count<<<nb_bin, 256, 0, stream>>>(src, dst, countD, countS, E, W);
    k_bucket_scan<<<1, 256, 0, stream>>>(countD, countS, baseD, baseS, curD, curS, E);
    k_bin_scatter<<<nb_bin, 256, 0, stream>>>(src, dst, curD, curS, pairD, pairS, E, W);
    k_build<<<NB, 256, 0, stream>>>(pairD, baseD, csr_in_src, row_in, dinv, N, W);
    k_build<<<NB, 256, 0, stream>>>(pairS, baseS, csr_out_e, row_out, nullptr, N, W);

    // edge-attr segment sum, then fused embed + mm1 -> B (g1)
    k_edge_sum<<<nb_nodes, 256, 0, stream>>>(ea, csr_out_e, row_out, se, N);
    k_embed_mm<<<nb_nodes, 256, 0, stream>>>(x, se, row_out, W_node, b_node,
                                             W_edge, b_edge, W_g1, dinv, B, N);

    // conv1 gather + mm2 -> C (g2); conv2 gather + mm3 -> B (g3)
    k_gather_mm<<<nb_nodes, 256, 0, stream>>>(csr_in_src, row_in, B, b_g1, dinv,
                                              W_g2, C, N);
    k_gather_mm<<<nb_nodes, 256, 0, stream>>>(csr_in_src, row_in, C, b_g2, dinv,
                                              W_g3, B, N);

    // conv3 gather + finalize + pool, then classifier
    k_gather_pool<<<nb_nodes, 256, 0, stream>>>(csr_in_src, row_in, B, b_g3,
                                                dinv, batch, sums, cnts, N);
    k_cls<<<G, 64, 0, stream>>>(sums, cnts, W_c1, b_c1, W_c2, b_c2, (float*)d_out);
}

// Round 5
// 557.443 us; speedup vs baseline: 3.7996x; 1.1261x over previous
//
#include <hip/hip_runtime.h>

#define NODE_DIM 128
#define HDIM 64
#define EDGE_DIM 32
#define NB 256          // buckets for CSR binning
#define WMAX 512        // max nodes per bucket (N <= NB*WMAX = 131072)
#define EPB 4096        // edges per block in binning kernels

__device__ __forceinline__ void f4_add(float4& a, const float4 b) {
    a.x += b.x; a.y += b.y; a.z += b.z; a.w += b.w;
}
__device__ __forceinline__ void f4_shfl_xor_add(float4& a, int m) {
    a.x += __shfl_xor(a.x, m, 64);
    a.y += __shfl_xor(a.y, m, 64);
    a.z += __shfl_xor(a.z, m, 64);
    a.w += __shfl_xor(a.w, m, 64);
}
__device__ __forceinline__ void f4_fma(float4& a, float s, const float4 w) {
    a.x = fmaf(s, w.x, a.x); a.y = fmaf(s, w.y, a.y);
    a.z = fmaf(s, w.z, a.z); a.w = fmaf(s, w.w, a.w);
}

// ---- pass 1: per-bucket edge counts (dst-keyed and src-keyed) ----
__global__ __launch_bounds__(256) void k_bin_count(const int* __restrict__ src,
        const int* __restrict__ dst, int* __restrict__ countD,
        int* __restrict__ countS, int E, int W) {
    __shared__ int hD[NB], hS[NB];
    int t = threadIdx.x;
    hD[t] = 0; hS[t] = 0;
    __syncthreads();
    int lo = blockIdx.x * EPB, hi = min(lo + EPB, E);
    for (int e = lo + t; e < hi; e += 256) {
        atomicAdd(&hD[dst[e] / W], 1);
        atomicAdd(&hS[src[e] / W], 1);
    }
    __syncthreads();
    if (hD[t]) atomicAdd(&countD[t], hD[t]);
    if (hS[t]) atomicAdd(&countS[t], hS[t]);
}

// ---- bucket exclusive scan (1 block): bases + mutable cursors ----
__global__ __launch_bounds__(256) void k_bucket_scan(const int* __restrict__ countD,
        const int* __restrict__ countS, int* __restrict__ baseD,
        int* __restrict__ baseS, int* __restrict__ curD, int* __restrict__ curS,
        int E) {
    __shared__ int tmp[NB];
    int t = threadIdx.x;
    int v = countD[t]; tmp[t] = v; __syncthreads();
    for (int off = 1; off < NB; off <<= 1) {
        int u = (t >= off) ? tmp[t - off] : 0; __syncthreads();
        tmp[t] += u; __syncthreads();
    }
    baseD[t] = tmp[t] - v; curD[t] = tmp[t] - v;
    if (t == NB - 1) baseD[NB] = E;
    __syncthreads();
    v = countS[t]; tmp[t] = v; __syncthreads();
    for (int off = 1; off < NB; off <<= 1) {
        int u = (t >= off) ? tmp[t - off] : 0; __syncthreads();
        tmp[t] += u; __syncthreads();
    }
    baseS[t] = tmp[t] - v; curS[t] = tmp[t] - v;
    if (t == NB - 1) baseS[NB] = E;
}

// ---- pass 2: scatter (key,val) pairs into bucket-grouped arrays ----
__global__ __launch_bounds__(256) void k_bin_scatter(const int* __restrict__ src,
        const int* __restrict__ dst, int* __restrict__ curD, int* __restrict__ curS,
        int2* __restrict__ pairD, int2* __restrict__ pairS, int E, int W) {
    __shared__ int hD[NB], hS[NB], bD[NB], bS[NB], oD[NB], oS[NB];
    int t = threadIdx.x;
    hD[t] = 0; hS[t] = 0; oD[t] = 0; oS[t] = 0;
    __syncthreads();
    int lo = blockIdx.x * EPB, hi = min(lo + EPB, E);
    for (int e = lo + t; e < hi; e += 256) {
        atomicAdd(&hD[dst[e] / W], 1);
        atomicAdd(&hS[src[e] / W], 1);
    }
    __syncthreads();
    if (hD[t]) bD[t] = atomicAdd(&curD[t], hD[t]);
    if (hS[t]) bS[t] = atomicAdd(&curS[t], hS[t]);
    __syncthreads();
    for (int e = lo + t; e < hi; e += 256) {
        int s = src[e], d = dst[e];
        int kb = d / W;
        int p = bD[kb] + atomicAdd(&oD[kb], 1);
        pairD[p] = make_int2(d, s);
        kb = s / W;
        p = bS[kb] + atomicAdd(&oS[kb], 1);
        pairS[p] = make_int2(s, e);
    }
}

// ---- pass 3: per-bucket CSR build ----
__global__ __launch_bounds__(256) void k_build(const int2* __restrict__ pairs,
        const int* __restrict__ base, int* __restrict__ csr, int* __restrict__ row,
        float* __restrict__ dinv, int N, int W) {
    __shared__ int cnt[WMAX], pref[WMAX], cur[WMAX];
    int b = blockIdx.x, t = threadIdx.x;
    int nbase = b * W;
    int wlen = min(W, N - nbase);
    int pb = base[b], pe = base[b + 1];
    for (int i = t; i < W; i += 256) cnt[i] = 0;
    __syncthreads();
    for (int j = pb + t; j < pe; j += 256)
        atomicAdd(&cnt[pairs[j].x - nbase], 1);
    __syncthreads();
    if (t < 64) {                       // wave0 exclusive scan of cnt[0..W)
        int run = 0;
        for (int c = 0; c < W; c += 64) {
            int i = c + t;
            int v = (i < W) ? cnt[i] : 0;
            int s = v;
            for (int off = 1; off < 64; off <<= 1) {
                int u = __shfl_up(s, off, 64);
                if (t >= off) s += u;
            }
            if (i < W) pref[i] = run + s - v;
            run += __shfl(s, 63, 64);
        }
    }
    __syncthreads();
    for (int i = t; i < wlen; i += 256) {
        row[nbase + i] = pb + pref[i];
        cur[i] = pref[i];
        if (dinv) dinv[nbase + i] = 1.0f / sqrtf((float)cnt[i] + 1.0f);
    }
    if (b == gridDim.x - 1 && t == 0) row[N] = pe;
    __syncthreads();
    for (int j = pb + t; j < pe; j += 256) {
        int2 pr = pairs[j];
        int idx = atomicAdd(&cur[pr.x - nbase], 1);
        csr[pb + idx] = pr.y;
    }
}

// ---- edge-attr segment sum by source: se[n][32] ----
__global__ __launch_bounds__(256) void k_edge_sum(const float* __restrict__ ea,
        const int* __restrict__ csr_out_e, const int* __restrict__ row_out,
        float* __restrict__ se, int n) {
    int g = threadIdx.x >> 6, lane = threadIdx.x & 63;
    int slot = lane >> 3, dq = lane & 7;
    int node = blockIdx.x * 4 + g;
    if (node >= n) return;
    int jb = row_out[node], je = row_out[node + 1];
    float4 acc = make_float4(0.f, 0.f, 0.f, 0.f);
    for (int base = jb; base < je; base += 64) {
        int cnt = min(64, je - base);
        int myidx = (base + lane < je) ? csr_out_e[base + lane] : 0;
#pragma unroll 4
        for (int t = 0; t < cnt; t += 8) {
            int which = t + slot;
            int e = __shfl(myidx, which, 64);
            if (which < cnt) {
                float4 v = *reinterpret_cast<const float4*>(
                    &ea[(size_t)e * EDGE_DIM + 4 * dq]);
                f4_add(acc, v);
            }
        }
    }
    f4_shfl_xor_add(acc, 8);
    f4_shfl_xor_add(acc, 16);
    f4_shfl_xor_add(acc, 32);
    if (slot == 0)
        *reinterpret_cast<float4*>(&se[(size_t)node * EDGE_DIM + 4 * dq]) = acc;
}

// ---- register-tiled fused embed GEMM:
// h = x@Wn + bn + se@We + outdeg*be;   g1 = dinv*(h@W1)
// 64-node tile/block; 256 thr = 8 o-thr x 32 m-thr; each thread 2 nodes x 8 outs
__global__ __launch_bounds__(256) void k_embed_mm2(const float* __restrict__ x,
        const float* __restrict__ se, const int* __restrict__ row_out,
        const float* __restrict__ dinv,
        const float* __restrict__ Wn, const float* __restrict__ bn,
        const float* __restrict__ We, const float* __restrict__ be,
        const float* __restrict__ W1, float* __restrict__ gout, int N) {
    __shared__ float xs[64][132];   // pad: rows 528B (16B-mult), banks 2-way max
    __shared__ float ses[64][36];
    __shared__ float hs[64][68];
    __shared__ float dv[64], od[64];
    const int tid = threadIdx.x;
    const int node0 = blockIdx.x * 64;
    const int o0 = (tid & 7) * 8;
    const int m0 = (tid >> 3) * 2;

    // ---- phase A: stage x, se, dinv, outdeg ----
#pragma unroll
    for (int rep = 0; rep < 8; rep++) {
        int idx = rep * 256 + tid;
        int m = idx >> 5, c4 = (idx & 31) * 4;
        if (node0 + m < N)
            *reinterpret_cast<float4*>(&xs[m][c4]) =
                *reinterpret_cast<const float4*>(&x[(size_t)(node0 + m) * NODE_DIM + c4]);
    }
#pragma unroll
    for (int rep = 0; rep < 2; rep++) {
        int idx = rep * 256 + tid;
        int m = idx >> 3, c4 = (idx & 7) * 4;
        if (node0 + m < N)
            *reinterpret_cast<float4*>(&ses[m][c4]) =
                *reinterpret_cast<const float4*>(&se[(size_t)(node0 + m) * EDGE_DIM + c4]);
    }
    if (tid < 64) {
        int node = node0 + tid;
        if (node < N) {
            dv[tid] = dinv[node];
            od[tid] = (float)(row_out[node + 1] - row_out[node]);
        } else { dv[tid] = 0.f; od[tid] = 0.f; }
    }
    __syncthreads();

    // ---- mm1: acc = bn + od*be + x@Wn + ses@We ----
    float4 bna = *reinterpret_cast<const float4*>(&bn[o0]);
    float4 bnb = *reinterpret_cast<const float4*>(&bn[o0 + 4]);
    float4 bea = *reinterpret_cast<const float4*>(&be[o0]);
    float4 beb = *reinterpret_cast<const float4*>(&be[o0 + 4]);
    float4 acc[2][2];
#pragma unroll
    for (int i = 0; i < 2; i++) {
        float odv = od[m0 + i];
        acc[i][0] = make_float4(fmaf(odv, bea.x, bna.x), fmaf(odv, bea.y, bna.y),
                                fmaf(odv, bea.z, bna.z), fmaf(odv, bea.w, bna.w));
        acc[i][1] = make_float4(fmaf(odv, beb.x, bnb.x), fmaf(odv, beb.y, bnb.y),
                                fmaf(odv, beb.z, bnb.z), fmaf(odv, beb.w, bnb.w));
    }
    for (int k = 0; k < NODE_DIM; k += 4) {
        float4 xv0 = *reinterpret_cast<const float4*>(&xs[m0][k]);
        float4 xv1 = *reinterpret_cast<const float4*>(&xs[m0 + 1][k]);
        float x0v[4] = {xv0.x, xv0.y, xv0.z, xv0.w};
        float x1v[4] = {xv1.x, xv1.y, xv1.z, xv1.w};
#pragma unroll
        for (int j = 0; j < 4; j++) {
            float4 wa = *reinterpret_cast<const float4*>(&Wn[(k + j) * HDIM + o0]);
            float4 wb = *reinterpret_cast<const float4*>(&Wn[(k + j) * HDIM + o0 + 4]);
            f4_fma(acc[0][0], x0v[j], wa); f4_fma(acc[0][1], x0v[j], wb);
            f4_fma(acc[1][0], x1v[j], wa); f4_fma(acc[1][1], x1v[j], wb);
        }
    }
    for (int k = 0; k < EDGE_DIM; k += 4) {
        float4 sv0 = *reinterpret_cast<const float4*>(&ses[m0][k]);
        float4 sv1 = *reinterpret_cast<const float4*>(&ses[m0 + 1][k]);
        float s0v[4] = {sv0.x, sv0.y, sv0.z, sv0.w};
        float s1v[4] = {sv1.x, sv1.y, sv1.z, sv1.w};
#pragma unroll
        for (int j = 0; j < 4; j++) {
            float4 wa = *reinterpret_cast<const float4*>(&We[(k + j) * HDIM + o0]);
            float4 wb = *reinterpret_cast<const float4*>(&We[(k + j) * HDIM + o0 + 4]);
            f4_fma(acc[0][0], s0v[j], wa); f4_fma(acc[0][1], s0v[j], wb);
            f4_fma(acc[1][0], s1v[j], wa); f4_fma(acc[1][1], s1v[j], wb);
        }
    }
#pragma unroll
    for (int i = 0; i < 2; i++) {
        *reinterpret_cast<float4*>(&hs[m0 + i][o0])     = acc[i][0];
        *reinterpret_cast<float4*>(&hs[m0 + i][o0 + 4]) = acc[i][1];
    }
    __syncthreads();

    // ---- mm2: g1 = dinv * (h @ W1) ----
    float4 a2[2][2];
#pragma unroll
    for (int i = 0; i < 2; i++) {
        a2[i][0] = make_float4(0.f, 0.f, 0.f, 0.f);
        a2[i][1] = make_float4(0.f, 0.f, 0.f, 0.f);
    }
    for (int k = 0; k < HDIM; k += 4) {
        float4 hv0 = *reinterpret_cast<const float4*>(&hs[m0][k]);
        float4 hv1 = *reinterpret_cast<const float4*>(&hs[m0 + 1][k]);
        float h0v[4] = {hv0.x, hv0.y, hv0.z, hv0.w};
        float h1v[4] = {hv1.x, hv1.y, hv1.z, hv1.w};
#pragma unroll
        for (int j = 0; j < 4; j++) {
            float4 wa = *reinterpret_cast<const float4*>(&W1[(k + j) * HDIM + o0]);
            float4 wb = *reinterpret_cast<const float4*>(&W1[(k + j) * HDIM + o0 + 4]);
            f4_fma(a2[0][0], h0v[j], wa); f4_fma(a2[0][1], h0v[j], wb);
            f4_fma(a2[1][0], h1v[j], wa); f4_fma(a2[1][1], h1v[j], wb);
        }
    }
#pragma unroll
    for (int i = 0; i < 2; i++) {
        int node = node0 + m0 + i;
        if (node < N) {
            float d = dv[m0 + i];
            float4 r0 = a2[i][0], r1 = a2[i][1];
            r0.x *= d; r0.y *= d; r0.z *= d; r0.w *= d;
            r1.x *= d; r1.y *= d; r1.z *= d; r1.w *= d;
            *reinterpret_cast<float4*>(&gout[(size_t)node * HDIM + o0])     = r0;
            *reinterpret_cast<float4*>(&gout[(size_t)node * HDIM + o0 + 4]) = r1;
        }
    }
}

// ---- fused gather + next-layer matmul ----
__global__ __launch_bounds__(256) void k_gather_mm(const int* __restrict__ csr_src,
        const int* __restrict__ row_in, const float* __restrict__ gbuf,
        const float* __restrict__ bin, const float* __restrict__ dinv,
        const float* __restrict__ W, float* __restrict__ gout, int n) {
    __shared__ float hs[4][HDIM];
    int g = threadIdx.x >> 6, lane = threadIdx.x & 63;
    int slot = lane >> 4, dq = lane & 15;
    int node = blockIdx.x * 4 + g;
    bool valid = node < n;
    float di = 0.f;
    float4 acc = make_float4(0.f, 0.f, 0.f, 0.f);
    if (valid) {
        di = dinv[node];
        if (slot == 0)
            acc = *reinterpret_cast<const float4*>(&gbuf[(size_t)node * HDIM + 4 * dq]);
        int jb = row_in[node], je = row_in[node + 1];
        for (int base = jb; base < je; base += 64) {
            int cnt = min(64, je - base);
            int myidx = (base + lane < je) ? csr_src[base + lane] : 0;
#pragma unroll 4
            for (int t = 0; t < cnt; t += 4) {
                int which = t + slot;
                int e = __shfl(myidx, which, 64);
                if (which < cnt) {
                    float4 v = *reinterpret_cast<const float4*>(
                        &gbuf[(size_t)e * HDIM + 4 * dq]);
                    f4_add(acc, v);
                }
            }
        }
        f4_shfl_xor_add(acc, 16);
        f4_shfl_xor_add(acc, 32);
        if (slot == 0) {
            float4 bq = *reinterpret_cast<const float4*>(&bin[4 * dq]);
            float4 z;
            z.x = fmaxf(fmaf(di, acc.x, bq.x), 0.f);
            z.y = fmaxf(fmaf(di, acc.y, bq.y), 0.f);
            z.z = fmaxf(fmaf(di, acc.z, bq.z), 0.f);
            z.w = fmaxf(fmaf(di, acc.w, bq.w), 0.f);
            *reinterpret_cast<float4*>(&hs[g][4 * dq]) = z;
        }
    }
    __syncthreads();
    if (!valid) return;
    float a = 0.f;
#pragma unroll
    for (int k = 0; k < HDIM; k++) a = fmaf(hs[g][k], W[k * HDIM + lane], a);
    gout[(size_t)node * HDIM + lane] = a * di;
}

// ---- conv3 gather + finalize + mean-pool (block-merged atomics) ----
__global__ __launch_bounds__(256) void k_gather_pool(const int* __restrict__ csr_src,
        const int* __restrict__ row_in, const float* __restrict__ gbuf,
        const float* __restrict__ bin, const float* __restrict__ dinv,
        const int* __restrict__ batch, float* __restrict__ sums,
        float* __restrict__ cnts, int n) {
    __shared__ float vs[4][HDIM];
    __shared__ int bs[4];
    int g = threadIdx.x >> 6, lane = threadIdx.x & 63;
    int slot = lane >> 4, dq = lane & 15;
    int node = blockIdx.x * 4 + g;
    bool valid = node < n;
    float di = 0.f;
    int b = -1;
    float4 acc = make_float4(0.f, 0.f, 0.f, 0.f);
    if (valid) {
        di = dinv[node];
        b = batch[node];
        if (slot == 0)
            acc = *reinterpret_cast<const float4*>(&gbuf[(size_t)node * HDIM + 4 * dq]);
        int jb = row_in[node], je = row_in[node + 1];
        for (int base = jb; base < je; base += 64) {
            int cnt = min(64, je - base);
            int myidx = (base + lane < je) ? csr_src[base + lane] : 0;
#pragma unroll 4
            for (int t = 0; t < cnt; t += 4) {
                int which = t + slot;
                int e = __shfl(myidx, which, 64);
                if (which < cnt) {
                    float4 v = *reinterpret_cast<const float4*>(
                        &gbuf[(size_t)e * HDIM + 4 * dq]);
                    f4_add(acc, v);
                }
            }
        }
        f4_shfl_xor_add(acc, 16);
        f4_shfl_xor_add(acc, 32);
        if (slot == 0) {
            float4 bq = *reinterpret_cast<const float4*>(&bin[4 * dq]);
            float4 z;
            z.x = fmaf(di, acc.x, bq.x);
            z.y = fmaf(di, acc.y, bq.y);
            z.z = fmaf(di, acc.z, bq.z);
            z.w = fmaf(di, acc.w, bq.w);
            *reinterpret_cast<float4*>(&vs[g][4 * dq]) = z;
        }
    }
    if (lane == 0) bs[g] = b;
    __syncthreads();
    bool same = (bs[0] >= 0 && bs[0] == bs[1] && bs[1] == bs[2] && bs[2] == bs[3]);
    if (same) {
        if (g == 0) {
            float t = vs[0][lane] + vs[1][lane] + vs[2][lane] + vs[3][lane];
            atomicAdd(&sums[(size_t)bs[0] * HDIM + lane], t);
            if (lane == 0) atomicAdd(&cnts[bs[0]], 4.0f);
        }
    } else if (valid) {
        atomicAdd(&sums[(size_t)b * HDIM + lane], vs[g][lane]);
        if (lane == 0) atomicAdd(&cnts[b], 1.0f);
    }
}

// ---- classifier ----
__global__ __launch_bounds__(64) void k_cls(const float* __restrict__ sums,
        const float* __restrict__ cnts, const float* __restrict__ W1,
        const float* __restrict__ b1, const float* __restrict__ W2,
        const float* __restrict__ b2, float* __restrict__ out) {
    __shared__ float gs[HDIM];
    __shared__ float zs[32];
    int b = blockIdx.x, t = threadIdx.x;
    float cnt = fmaxf(cnts[b], 1.0f);
    gs[t] = sums[(size_t)b * HDIM + t] / cnt;
    __syncthreads();
    if (t < 32) {
        float a = b1[t];
#pragma unroll
        for (int k = 0; k < HDIM; k++) a = fmaf(gs[k], W1[k * 32 + t], a);
        zs[t] = fmaxf(a, 0.0f);
    }
    __syncthreads();
    if (t == 0) {
        float a = b2[0];
#pragma unroll
        for (int k = 0; k < 32; k++) a = fmaf(zs[k], W2[k], a);
        out[b] = a;
    }
}

extern "C" void kernel_launch(void* const* d_in, const int* in_sizes, int n_in,
                              void* d_out, int out_size, void* d_ws, size_t ws_size,
                              hipStream_t stream) {
    const float* x      = (const float*)d_in[0];
    const int*   ei     = (const int*)d_in[1];
    const float* ea     = (const float*)d_in[2];
    const int*   batch  = (const int*)d_in[3];
    const float* W_node = (const float*)d_in[4];
    const float* b_node = (const float*)d_in[5];
    const float* W_edge = (const float*)d_in[6];
    const float* b_edge = (const float*)d_in[7];
    const float* W_g1   = (const float*)d_in[8];
    const float* b_g1   = (const float*)d_in[9];
    const float* W_g2   = (const float*)d_in[10];
    const float* b_g2   = (const float*)d_in[11];
    const float* W_g3   = (const float*)d_in[12];
    const float* b_g3   = (const float*)d_in[13];
    const float* W_c1   = (const float*)d_in[14];
    const float* b_c1   = (const float*)d_in[15];
    const float* W_c2   = (const float*)d_in[16];
    const float* b_c2   = (const float*)d_in[17];

    const int N = in_sizes[0] / NODE_DIM;
    const int E = in_sizes[2] / EDGE_DIM;
    const int G = out_size;
    const int W = (N + NB - 1) / NB;
    const int* src = ei;
    const int* dst = ei + E;

    char* ws = (char*)d_ws;
    size_t off = 0;
    auto carve = [&](size_t bytes) -> void* {
        void* p = ws + off;
        off += (bytes + 255) & ~(size_t)255;
        return p;
    };
    int*   counts     = (int*)carve((size_t)2 * NB * 4);
    int*   baseD      = (int*)carve((size_t)(NB + 1) * 4);
    int*   baseS      = (int*)carve((size_t)(NB + 1) * 4);
    int*   curD       = (int*)carve((size_t)NB * 4);
    int*   curS       = (int*)carve((size_t)NB * 4);
    int*   row_in     = (int*)carve((size_t)(N + 1) * 4);
    int*   row_out    = (int*)carve((size_t)(N + 1) * 4);
    int*   csr_in_src = (int*)carve((size_t)E * 4);
    int*   csr_out_e  = (int*)carve((size_t)E * 4);
    float* dinv       = (float*)carve((size_t)N * 4);
    float* se         = (float*)carve((size_t)N * EDGE_DIM * 4);
    float* B          = (float*)carve((size_t)N * HDIM * 4);
    float* C          = (float*)carve((size_t)N * HDIM * 4);
    float* sums       = (float*)carve((size_t)G * HDIM * 4);
    float* cnts       = (float*)carve((size_t)G * 4);
    int*   countD = counts, *countS = counts + NB;
    int2*  pairD = (int2*)B;     // aliases B (consumed before B first written)
    int2*  pairS = (int2*)C;     // aliases C

    hipMemsetAsync(counts, 0, (size_t)2 * NB * 4, stream);
    hipMemsetAsync(sums, 0, (size_t)G * HDIM * 4, stream);
    hipMemsetAsync(cnts, 0, (size_t)G * 4, stream);

    const int nb_nodes = (N + 3) / 4;
    const int nb_bin   = (E + EPB - 1) / EPB;
    const int nb_tiles = (N + 63) / 64;

    // CSR construction via bucket binning
    k_bin_count<<<nb_bin, 256, 0, stream>>>(src, dst, countD, countS, E, W);
    k_bucket_scan<<<1, 256, 0, stream>>>(countD, countS, baseD, baseS, curD, curS, E);
    k_bin_scatter<<<nb_bin, 256, 0, stream>>>(src, dst, curD, curS, pairD, pairS, E, W);
    k_build<<<NB, 256, 0, stream>>>(pairD, baseD, csr_in_src, row_in, dinv, N, W);
    k_build<<<NB, 256, 0, stream>>>(pairS, baseS, csr_out_e, row_out, nullptr, N, W);

    // edge-attr segment sum, then register-tiled fused embed + mm1 -> B (g1)
    k_edge_sum<<<nb_nodes, 256, 0, stream>>>(ea, csr_out_e, row_out, se, N);
    k_embed_mm2<<<nb_tiles, 256, 0, stream>>>(x, se, row_out, dinv, W_node, b_node,
                                              W_edge, b_edge, W_g1, B, N);

    // conv1 gather + mm2 -> C (g2); conv2 gather + mm3 -> B (g3)
    k_gather_mm<<<nb_nodes, 256, 0, stream>>>(csr_in_src, row_in, B, b_g1, dinv,
                                              W_g2, C, N);
    k_gather_mm<<<nb_nodes, 256, 0, stream>>>(csr_in_src, row_in, C, b_g2, dinv,
                                              W_g3, B, N);

    // conv3 gather + finalize + pool, then classifier
    k_gather_pool<<<nb_nodes, 256, 0, stream>>>(csr_in_src, row_in, B, b_g3,
                                                dinv, batch, sums, cnts, N);
    k_cls<<<G, 64, 0, stream>>>(sums, cnts, W_c1, b_c1, W_c2, b_c2, (float*)d_out);
}